// Round 5
// baseline (417.859 us; speedup 1.0000x reference)
//
#include <hip/hip_runtime.h>
#include <hip/hip_bf16.h>
#include <math.h>

// ---------------- problem constants ----------------
namespace {
constexpr int kN  = 1024;
constexpr int kK  = 768;          // 12 * 64 fused K
// workspace layout (bytes)
constexpr size_t WS_FUSED = 0;                               // [65536][64] f32 = 16 MB
constexpr size_t WS_CTH   = (size_t)65536 * 64 * 4;          // [128][768] bf16 hi
constexpr size_t WS_CTL   = WS_CTH + (size_t)128 * 768 * 2;  // [128][768] bf16 lo
constexpr size_t WS_CONST = WS_CTL + (size_t)128 * 768 * 2;  // [128] f32
constexpr size_t WS_LMEAN = WS_CONST + 512;                  // [64][32] f32
constexpr size_t WS_GMEAN = WS_LMEAN + (size_t)64 * 32 * 4;  // [64][32] f32
}

typedef __attribute__((ext_vector_type(4))) float f32x4;
typedef __attribute__((ext_vector_type(8))) short bf16x8;

__device__ __forceinline__ short to_bf16(float f) {
    __hip_bfloat16 h = __float2bfloat16(f);   // RNE
    return *reinterpret_cast<short*>(&h);
}
__device__ __forceinline__ float bf16_to_f32(short s) {
    unsigned u = ((unsigned)(unsigned short)s) << 16;
    return __uint_as_float(u);
}
// exact 2-term split: v = hi + lo + O(2^-18 |v|)
__device__ __forceinline__ void split_bf16(float v, short& hi, short& lo) {
    hi = to_bf16(v);
    lo = to_bf16(v - bf16_to_f32(hi));
}

// ====================================================================
// prep: grid 128 (one block per memory slot mm).
// C[mm][s*64+h] = sum_p W[h,p] * bank[s,p]  -> split into CtH/CtL bf16 planes
// constv[mm] = sum_{s,p} bq[p]*bank[s,p];  bank means.
// ====================================================================
__global__ __launch_bounds__(256) void dcmn_prep(
    const float* __restrict__ Gb,   // [64][6][32]
    const float* __restrict__ Lb,   // [64][12][32]
    const float* __restrict__ Wq,   // [64][32]
    const float* __restrict__ bq,   // [32]
    short* __restrict__ CtH,        // [128][768] bf16 hi
    short* __restrict__ CtL,        // [128][768] bf16 lo
    float* __restrict__ constv,     // [128]
    float* __restrict__ Lmean,      // [64][32]
    float* __restrict__ Gmean)      // [64][32]
{
    __shared__ float Ws[2048];      // W[h][p]
    __shared__ float bank[384];     // [s][p], s=0..11
    const int t = threadIdx.x, mm = blockIdx.x;

    for (int i = t; i < 2048; i += 256) Ws[i] = Wq[i];
    for (int i = t; i < 384; i += 256) {
        const int s = i >> 5, p = i & 31;
        bank[i] = (mm < 64) ? Lb[mm * 384 + i]
                            : 0.5f * Gb[(mm - 64) * 192 + (s >> 1) * 32 + p];
    }
    __syncthreads();

    for (int i = t; i < kK; i += 256) {
        const int s = i >> 6, h = i & 63;
        float a = 0.f;
#pragma unroll
        for (int p = 0; p < 32; p++) a = fmaf(Ws[h * 32 + p], bank[s * 32 + p], a);
        short hi, lo;
        split_bf16(a, hi, lo);
        CtH[(size_t)mm * kK + i] = hi;
        CtL[(size_t)mm * kK + i] = lo;
    }
    if (t < 32) {
        float a = 0.f;
#pragma unroll
        for (int s = 0; s < 12; s++) a += bank[s * 32 + t];
        if (mm < 64) Lmean[mm * 32 + t] = a * (1.f / 12.f);
        else         Gmean[(mm - 64) * 32 + t] = a * (1.f / 6.f);
    }
    if (t == 0) {
        float c = 0.f;
        for (int i = 0; i < 384; i++) c += bq[i & 31] * bank[i];
        constv[mm] = c;
    }
}

// ====================================================================
// main: GEMM [65536,768]@[768,128] in split-bf16 (3 MFMA passes:
// aH*bH + aL*bH + aH*bL) + softmax/ctx epilogue.
// Block = 64 rows x 128 cols, 4 waves; K in 12 chunks of 64.
// LDS tiles are UNPADDED ([row][64] shorts) with XOR swizzle on the
// 8-short group index (g ^= row&7) to break bank aliasing.
// B planes staged via global_load_lds DMA (width 16): linear LDS dest,
// source address pre-swizzled with the SAME involution the MFMA read
// applies (rule-21). Issued before stage-A so DMA latency hides under
// stage-A's split-bf16 VALU work; the compiler's vmcnt(0) drain before
// s_barrier guarantees completion before MFMA reads.
// GEMM phase: AsH/AsL 8KB each + BsH/BsL 16KB each = 48KB;
// epilogue reuse needs 50KB -> LDS 51200B -> 3 blocks/CU.
// ====================================================================
__global__ __launch_bounds__(256, 3) void dcmn_main(
    const float* __restrict__ hist,   // [65536][768]
    const short* __restrict__ CtH,    // [128][768] bf16 hi
    const short* __restrict__ CtL,    // [128][768] bf16 lo
    const float* __restrict__ constv, // [128]
    const float* __restrict__ Lmean,  // [64][32]
    const float* __restrict__ Gmean,  // [64][32]
    float* __restrict__ fused)        // [65536][64]
{
    __shared__ char smraw[51200];
    short* AsH = (short*)smraw;              // [64][64]
    short* AsL = (short*)(smraw + 8192);     // [64][64]
    short* BsH = (short*)(smraw + 16384);    // [128][64]
    short* BsL = (short*)(smraw + 32768);    // [128][64]

    const int t = threadIdx.x, blk = blockIdx.x;
    const int wv = t >> 6, ln = t & 63;
    const int l15 = ln & 15, hi = ln >> 4;
    const int swz = l15 & 7;                 // frag-row swizzle (row&7 == l15&7)

    f32x4 acc[8];
#pragma unroll
    for (int i = 0; i < 8; i++) acc[i] = (f32x4){0.f, 0.f, 0.f, 0.f};

    const size_t histBase = (size_t)blk * 64 * kK;
    const int arow = wv * 16 + l15;

#pragma unroll 1
    for (int kc = 0; kc < 12; kc++) {
        __syncthreads();
        // ---- stage B first: async DMA, both planes (overlaps stage-A VALU) ----
        // dst slot (mm, g') holds src group g = g' ^ (mm&7); dst byte = idx*16
        // (linear in lane => wave-uniform base + lane*16, as global_load_lds needs)
#pragma unroll
        for (int j = 0; j < 4; j++) {
            const int idx = t + 256 * j;        // 1024 x 16B per plane
            const int mm  = idx >> 3, g = idx & 7;
            const size_t srcOff = (size_t)mm * kK + kc * 64 + ((g ^ (mm & 7)) << 3);
            __builtin_amdgcn_global_load_lds(
                (const __attribute__((address_space(1))) void*)(CtH + srcOff),
                (__attribute__((address_space(3))) void*)(BsH + idx * 8), 16, 0, 0);
            __builtin_amdgcn_global_load_lds(
                (const __attribute__((address_space(1))) void*)(CtL + srcOff),
                (__attribute__((address_space(3))) void*)(BsL + idx * 8), 16, 0, 0);
        }
        // ---- stage A: 64 rows x 64 floats -> split bf16, swizzled ----
#pragma unroll
        for (int i = 0; i < 2; i++) {
            const int c = 2 * t + i;            // 512 groups of 8
            const int r = c >> 3, g = c & 7;
            const float* src = hist + histBase + (size_t)r * kK + kc * 64 + g * 8;
            const float4 v0 = *(const float4*)src;
            const float4 v1 = *(const float4*)(src + 4);
            const float vv[8] = {v0.x, v0.y, v0.z, v0.w, v1.x, v1.y, v1.z, v1.w};
            bf16x8 oh, ol;
#pragma unroll
            for (int e = 0; e < 8; e++) {
                short h8, l8;
                split_bf16(vv[e], h8, l8);
                oh[e] = h8; ol[e] = l8;
            }
            const int dst = r * 64 + ((g ^ (r & 7)) << 3);
            *(bf16x8*)&AsH[dst] = oh;
            *(bf16x8*)&AsL[dst] = ol;
        }
        __syncthreads();
        // ---- MFMA: 2 k-steps x 8 col-tiles x 3 passes ----
#pragma unroll
        for (int kk = 0; kk < 2; kk++) {
            const int ag = ((kk * 4 + hi) ^ swz) << 3;
            const bf16x8 aH = *(const bf16x8*)&AsH[arow * 64 + ag];
            const bf16x8 aL = *(const bf16x8*)&AsL[arow * 64 + ag];
#pragma unroll
            for (int ct = 0; ct < 8; ct++) {
                const int brow = ct * 16 + l15;
                const bf16x8 bH = *(const bf16x8*)&BsH[brow * 64 + ag];
                const bf16x8 bL = *(const bf16x8*)&BsL[brow * 64 + ag];
                acc[ct] = __builtin_amdgcn_mfma_f32_16x16x32_bf16(aH, bH, acc[ct], 0, 0, 0);
                acc[ct] = __builtin_amdgcn_mfma_f32_16x16x32_bf16(aL, bH, acc[ct], 0, 0, 0);
                acc[ct] = __builtin_amdgcn_mfma_f32_16x16x32_bf16(aH, bL, acc[ct], 0, 0, 0);
            }
        }
    }

    __syncthreads();   // all MFMA LDS reads done; repurpose LDS
    float* SIMT = (float*)smraw;             // [128][68] (col x row) 34816 B
    float* ML   = (float*)(smraw + 34816);   // [64][32]
    float* MG   = (float*)(smraw + 43008);   // [64][32]

    // ---- write sims + folded bias, transposed: SIMT[col][row] ----
    // C/D layout: col = lane&15, row(16-tile) = (lane>>4)*4 + reg
#pragma unroll
    for (int ct = 0; ct < 8; ct++) {
        const int col = ct * 16 + l15;
        const float cv = constv[col];
        float4 o = {acc[ct][0] + cv, acc[ct][1] + cv, acc[ct][2] + cv, acc[ct][3] + cv};
        *(float4*)&SIMT[col * 68 + wv * 16 + hi * 4] = o;
    }
    for (int i = t; i < 512; i += 256) {
        ((float4*)ML)[i] = ((const float4*)Lmean)[i];
        ((float4*)MG)[i] = ((const float4*)Gmean)[i];
    }
    __syncthreads();

    // ---- epilogue: per-row softmax over 64 memories + ctx ----
    {
        const int r    = t & 63;
        const int qd   = t >> 6;
        const int side = qd & 1;
        const int p0   = (qd >> 1) * 16;
        const float* srow = &SIMT[side * 64 * 68 + r];
        const float* mean = (side ? MG : ML) + p0;

        float mx = -1e30f;
#pragma unroll 4
        for (int m = 0; m < 64; m++) mx = fmaxf(mx, srow[m * 68]);

        float den = 0.f;
        float4 c0 = {0,0,0,0}, c1 = {0,0,0,0}, c2 = {0,0,0,0}, c3 = {0,0,0,0};
#pragma unroll 4
        for (int m = 0; m < 64; m++) {
            const float w = __expf(srow[m * 68] - mx);
            den += w;
            const float* mr = mean + m * 32;     // wave-uniform -> LDS broadcast
            const float4 m0 = *(const float4*)(mr);
            const float4 m1 = *(const float4*)(mr + 4);
            const float4 m2 = *(const float4*)(mr + 8);
            const float4 m3 = *(const float4*)(mr + 12);
            c0.x = fmaf(w, m0.x, c0.x); c0.y = fmaf(w, m0.y, c0.y);
            c0.z = fmaf(w, m0.z, c0.z); c0.w = fmaf(w, m0.w, c0.w);
            c1.x = fmaf(w, m1.x, c1.x); c1.y = fmaf(w, m1.y, c1.y);
            c1.z = fmaf(w, m1.z, c1.z); c1.w = fmaf(w, m1.w, c1.w);
            c2.x = fmaf(w, m2.x, c2.x); c2.y = fmaf(w, m2.y, c2.y);
            c2.z = fmaf(w, m2.z, c2.z); c2.w = fmaf(w, m2.w, c2.w);
            c3.x = fmaf(w, m3.x, c3.x); c3.y = fmaf(w, m3.y, c3.y);
            c3.z = fmaf(w, m3.z, c3.z); c3.w = fmaf(w, m3.w, c3.w);
        }
        const float sc = 1.f / den;
        float4* fp = (float4*)&fused[(size_t)(blk * 64 + r) * 64 + side * 32 + p0];
        float4 o0 = {c0.x*sc, c0.y*sc, c0.z*sc, c0.w*sc};
        float4 o1 = {c1.x*sc, c1.y*sc, c1.z*sc, c1.w*sc};
        float4 o2 = {c2.x*sc, c2.y*sc, c2.z*sc, c2.w*sc};
        float4 o3 = {c3.x*sc, c3.y*sc, c3.z*sc, c3.w*sc};
        fp[0] = o0; fp[1] = o1; fp[2] = o2; fp[3] = o3;
    }
}

// ====================================================================
// out: per block = one node n. nw = emb[n] @ pool (LDS), fused staged
// TRANSPOSED (fsT[f][b]) so inner loop is 2x ds_read_b128 per f.
// ====================================================================
__global__ __launch_bounds__(256) void dcmn_out(
    const float* __restrict__ emb,    // [1024][16]
    const float* __restrict__ pool,   // [16][64][64]
    const float* __restrict__ fused,  // [65536][64]
    float* __restrict__ out)          // [64][1024][64]
{
    __shared__ float nw[64 * 68];    // nodeW [f][h]
    __shared__ float fsT[64 * 68];   // fused transposed [f][b]
    __shared__ float es[16];
    const int t = threadIdx.x, n = blockIdx.x;

    if (t < 16) es[t] = emb[n * 16 + t];
#pragma unroll
    for (int i = 0; i < 4; i++) {
        const int idx = t + 256 * i;             // 1024 float4
        const int b = idx >> 4, c4 = idx & 15;
        const float4 v = *(const float4*)&fused[((size_t)b * kN + n) * 64 + c4 * 4];
        fsT[(c4 * 4 + 0) * 68 + b] = v.x;
        fsT[(c4 * 4 + 1) * 68 + b] = v.y;
        fsT[(c4 * 4 + 2) * 68 + b] = v.z;
        fsT[(c4 * 4 + 3) * 68 + b] = v.w;
    }
    __syncthreads();

    // node_w: 4096 outputs, K=16 (pool L2-resident, coalesced over h)
#pragma unroll
    for (int i = 0; i < 16; i++) {
        const int idx = t + 256 * i;
        const int f = idx >> 6, h = idx & 63;
        float a = 0.f;
#pragma unroll
        for (int d = 0; d < 16; d++)
            a = fmaf(es[d], pool[(d * 64 + f) * 64 + h], a);
        nw[f * 68 + h] = a;
    }
    __syncthreads();

    // out[b][h] = sum_f fsT[f][b] * nw[f][h]; thread tile 4b x 4h
    const int tb = t >> 4;      // b = tb*4 + i
    const int th = t & 15;      // h = th*4 + j  (h fastest -> coalesced stores)
    f32x4 o0 = {0,0,0,0}, o1 = {0,0,0,0}, o2 = {0,0,0,0}, o3 = {0,0,0,0};
#pragma unroll 8
    for (int f = 0; f < 64; f++) {
        const f32x4 a = *(const f32x4*)&fsT[f * 68 + tb * 4];
        const f32x4 w = *(const f32x4*)&nw[f * 68 + th * 4];
        o0 += w * a.x;
        o1 += w * a.y;
        o2 += w * a.z;
        o3 += w * a.w;
    }
    *(f32x4*)&out[((size_t)(tb * 4 + 0) * kN + n) * 64 + th * 4] = o0;
    *(f32x4*)&out[((size_t)(tb * 4 + 1) * kN + n) * 64 + th * 4] = o1;
    *(f32x4*)&out[((size_t)(tb * 4 + 2) * kN + n) * 64 + th * 4] = o2;
    *(f32x4*)&out[((size_t)(tb * 4 + 3) * kN + n) * 64 + th * 4] = o3;
}

// ====================================================================
extern "C" void kernel_launch(void* const* d_in, const int* in_sizes, int n_in,
                              void* d_out, int out_size, void* d_ws, size_t ws_size,
                              hipStream_t stream) {
    (void)in_sizes; (void)n_in; (void)out_size; (void)ws_size;
    const float* hist = (const float*)d_in[0];   // h_history
    const float* Gb   = (const float*)d_in[1];   // global_memory_bank
    const float* Lb   = (const float*)d_in[2];   // local_memory_bank
    const float* Wq   = (const float*)d_in[3];   // W_q
    const float* bq   = (const float*)d_in[4];   // b_q
    const float* emb  = (const float*)d_in[5];   // node_embedding
    const float* pool = (const float*)d_in[6];   // weight_pool
    float* outp = (float*)d_out;

    char* ws = (char*)d_ws;
    float* fused  = (float*)(ws + WS_FUSED);
    short* CtH    = (short*)(ws + WS_CTH);
    short* CtL    = (short*)(ws + WS_CTL);
    float* constv = (float*)(ws + WS_CONST);
    float* Lmean  = (float*)(ws + WS_LMEAN);
    float* Gmean  = (float*)(ws + WS_GMEAN);

    hipLaunchKernelGGL(dcmn_prep, dim3(128), dim3(256), 0, stream,
                       Gb, Lb, Wq, bq, CtH, CtL, constv, Lmean, Gmean);
    hipLaunchKernelGGL(dcmn_main, dim3(1024), dim3(256), 0, stream,
                       hist, CtH, CtL, constv, Lmean, Gmean, fused);
    hipLaunchKernelGGL(dcmn_out, dim3(1024), dim3(256), 0, stream,
                       emb, pool, fused, outp);
}

// Round 6
// 413.401 us; speedup vs baseline: 1.0108x; 1.0108x over previous
//
#include <hip/hip_runtime.h>
#include <hip/hip_bf16.h>
#include <math.h>

// ---------------- problem constants ----------------
namespace {
constexpr int kN  = 1024;
constexpr int kK  = 768;          // 12 * 64 fused K
// workspace layout (bytes)
constexpr size_t WS_FUSED = 0;                               // [65536][64] f32 = 16 MB
constexpr size_t WS_CTH   = (size_t)65536 * 64 * 4;          // [128][768] bf16 hi
constexpr size_t WS_CTL   = WS_CTH + (size_t)128 * 768 * 2;  // [128][768] bf16 lo
constexpr size_t WS_CONST = WS_CTL + (size_t)128 * 768 * 2;  // [128] f32
constexpr size_t WS_LMEAN = WS_CONST + 512;                  // [64][32] f32
constexpr size_t WS_GMEAN = WS_LMEAN + (size_t)64 * 32 * 4;  // [64][32] f32
}

typedef __attribute__((ext_vector_type(4))) float f32x4;
typedef __attribute__((ext_vector_type(8))) short bf16x8;

__device__ __forceinline__ short to_bf16(float f) {
    __hip_bfloat16 h = __float2bfloat16(f);   // RNE
    return *reinterpret_cast<short*>(&h);
}
__device__ __forceinline__ float bf16_to_f32(short s) {
    unsigned u = ((unsigned)(unsigned short)s) << 16;
    return __uint_as_float(u);
}
// exact 2-term split: v = hi + lo + O(2^-18 |v|)
__device__ __forceinline__ void split_bf16(float v, short& hi, short& lo) {
    hi = to_bf16(v);
    lo = to_bf16(v - bf16_to_f32(hi));
}

// ====================================================================
// prep: grid 128 (one block per memory slot mm).
// C[mm][s*64+h] = sum_p W[h,p] * bank[s,p]  -> split into CtH/CtL bf16 planes
// constv[mm] = sum_{s,p} bq[p]*bank[s,p];  bank means.
// ====================================================================
__global__ __launch_bounds__(256) void dcmn_prep(
    const float* __restrict__ Gb,   // [64][6][32]
    const float* __restrict__ Lb,   // [64][12][32]
    const float* __restrict__ Wq,   // [64][32]
    const float* __restrict__ bq,   // [32]
    short* __restrict__ CtH,        // [128][768] bf16 hi
    short* __restrict__ CtL,        // [128][768] bf16 lo
    float* __restrict__ constv,     // [128]
    float* __restrict__ Lmean,      // [64][32]
    float* __restrict__ Gmean)      // [64][32]
{
    __shared__ float Ws[2048];      // W[h][p]
    __shared__ float bank[384];     // [s][p], s=0..11
    const int t = threadIdx.x, mm = blockIdx.x;

    for (int i = t; i < 2048; i += 256) Ws[i] = Wq[i];
    for (int i = t; i < 384; i += 256) {
        const int s = i >> 5, p = i & 31;
        bank[i] = (mm < 64) ? Lb[mm * 384 + i]
                            : 0.5f * Gb[(mm - 64) * 192 + (s >> 1) * 32 + p];
    }
    __syncthreads();

    for (int i = t; i < kK; i += 256) {
        const int s = i >> 6, h = i & 63;
        float a = 0.f;
#pragma unroll
        for (int p = 0; p < 32; p++) a = fmaf(Ws[h * 32 + p], bank[s * 32 + p], a);
        short hi, lo;
        split_bf16(a, hi, lo);
        CtH[(size_t)mm * kK + i] = hi;
        CtL[(size_t)mm * kK + i] = lo;
    }
    if (t < 32) {
        float a = 0.f;
#pragma unroll
        for (int s = 0; s < 12; s++) a += bank[s * 32 + t];
        if (mm < 64) Lmean[mm * 32 + t] = a * (1.f / 12.f);
        else         Gmean[(mm - 64) * 32 + t] = a * (1.f / 6.f);
    }
    if (t == 0) {
        float c = 0.f;
        for (int i = 0; i < 384; i++) c += bq[i & 31] * bank[i];
        constv[mm] = c;
    }
}

// ====================================================================
// main: GEMM [65536,768]@[768,128] in split-bf16 (3 MFMA passes:
// aH*bH + aL*bH + aH*bL) + softmax/ctx epilogue.
// Block = 64 rows x 128 cols, 4 waves; K in 12 chunks of 64.
// LDS tiles are UNPADDED ([row][64] shorts) with XOR swizzle on the
// 8-short group index (g ^= row&7) to break bank aliasing.
// B staged via VGPR int4 copies (CtH/CtL are L2-resident; the
// global_load_lds DMA variant measured +4.2us — reverted).
// GEMM phase: AsH/AsL 8KB each + BsH/BsL 16KB each = 48KB;
// epilogue reuse needs 50KB -> LDS 51200B -> 3 blocks/CU.
// ====================================================================
__global__ __launch_bounds__(256, 3) void dcmn_main(
    const float* __restrict__ hist,   // [65536][768]
    const short* __restrict__ CtH,    // [128][768] bf16 hi
    const short* __restrict__ CtL,    // [128][768] bf16 lo
    const float* __restrict__ constv, // [128]
    const float* __restrict__ Lmean,  // [64][32]
    const float* __restrict__ Gmean,  // [64][32]
    float* __restrict__ fused)        // [65536][64]
{
    __shared__ char smraw[51200];
    short* AsH = (short*)smraw;              // [64][64]
    short* AsL = (short*)(smraw + 8192);     // [64][64]
    short* BsH = (short*)(smraw + 16384);    // [128][64]
    short* BsL = (short*)(smraw + 32768);    // [128][64]

    const int t = threadIdx.x, blk = blockIdx.x;
    const int wv = t >> 6, ln = t & 63;
    const int l15 = ln & 15, hi = ln >> 4;
    const int swz = l15 & 7;                 // frag-row swizzle (row&7 == l15&7)

    f32x4 acc[8];
#pragma unroll
    for (int i = 0; i < 8; i++) acc[i] = (f32x4){0.f, 0.f, 0.f, 0.f};

    const size_t histBase = (size_t)blk * 64 * kK;
    const int arow = wv * 16 + l15;

#pragma unroll 1
    for (int kc = 0; kc < 12; kc++) {
        __syncthreads();
        // ---- stage A: 64 rows x 64 floats -> split bf16, swizzled ----
#pragma unroll
        for (int i = 0; i < 2; i++) {
            const int c = 2 * t + i;            // 512 groups of 8
            const int r = c >> 3, g = c & 7;
            const float* src = hist + histBase + (size_t)r * kK + kc * 64 + g * 8;
            const float4 v0 = *(const float4*)src;
            const float4 v1 = *(const float4*)(src + 4);
            const float vv[8] = {v0.x, v0.y, v0.z, v0.w, v1.x, v1.y, v1.z, v1.w};
            bf16x8 oh, ol;
#pragma unroll
            for (int e = 0; e < 8; e++) {
                short h8, l8;
                split_bf16(vv[e], h8, l8);
                oh[e] = h8; ol[e] = l8;
            }
            const int dst = r * 64 + ((g ^ (r & 7)) << 3);
            *(bf16x8*)&AsH[dst] = oh;
            *(bf16x8*)&AsL[dst] = ol;
        }
        // ---- stage B: 2 planes x 128 rows x 64 k (int4 copies, swizzled) ----
#pragma unroll
        for (int j = 0; j < 8; j++) {
            const int idx = t + 256 * j;        // 2048 int4
            const int pl  = idx >> 10;          // 0:H 1:L (wave-uniform per j)
            const int rem = idx & 1023;
            const int mm  = rem >> 3, g = rem & 7;
            const short* srcp = (pl ? CtL : CtH) + (size_t)mm * kK + kc * 64 + g * 8;
            short* dstp = (pl ? BsL : BsH) + mm * 64 + ((g ^ (mm & 7)) << 3);
            *(int4*)dstp = *(const int4*)srcp;
        }
        __syncthreads();
        // ---- MFMA: 2 k-steps x 8 col-tiles x 3 passes ----
#pragma unroll
        for (int kk = 0; kk < 2; kk++) {
            const int ag = ((kk * 4 + hi) ^ swz) << 3;
            const bf16x8 aH = *(const bf16x8*)&AsH[arow * 64 + ag];
            const bf16x8 aL = *(const bf16x8*)&AsL[arow * 64 + ag];
#pragma unroll
            for (int ct = 0; ct < 8; ct++) {
                const int brow = ct * 16 + l15;
                const bf16x8 bH = *(const bf16x8*)&BsH[brow * 64 + ag];
                const bf16x8 bL = *(const bf16x8*)&BsL[brow * 64 + ag];
                acc[ct] = __builtin_amdgcn_mfma_f32_16x16x32_bf16(aH, bH, acc[ct], 0, 0, 0);
                acc[ct] = __builtin_amdgcn_mfma_f32_16x16x32_bf16(aL, bH, acc[ct], 0, 0, 0);
                acc[ct] = __builtin_amdgcn_mfma_f32_16x16x32_bf16(aH, bL, acc[ct], 0, 0, 0);
            }
        }
    }

    __syncthreads();   // all MFMA LDS reads done; repurpose LDS
    float* SIMT = (float*)smraw;             // [128][68] (col x row) 34816 B
    float* ML   = (float*)(smraw + 34816);   // [64][32]
    float* MG   = (float*)(smraw + 43008);   // [64][32]

    // ---- write sims + folded bias, transposed: SIMT[col][row] ----
    // C/D layout: col = lane&15, row(16-tile) = (lane>>4)*4 + reg
#pragma unroll
    for (int ct = 0; ct < 8; ct++) {
        const int col = ct * 16 + l15;
        const float cv = constv[col];
        float4 o = {acc[ct][0] + cv, acc[ct][1] + cv, acc[ct][2] + cv, acc[ct][3] + cv};
        *(float4*)&SIMT[col * 68 + wv * 16 + hi * 4] = o;
    }
    for (int i = t; i < 512; i += 256) {
        ((float4*)ML)[i] = ((const float4*)Lmean)[i];
        ((float4*)MG)[i] = ((const float4*)Gmean)[i];
    }
    __syncthreads();

    // ---- epilogue: per-row softmax over 64 memories + ctx ----
    {
        const int r    = t & 63;
        const int qd   = t >> 6;
        const int side = qd & 1;
        const int p0   = (qd >> 1) * 16;
        const float* srow = &SIMT[side * 64 * 68 + r];
        const float* mean = (side ? MG : ML) + p0;

        float mx = -1e30f;
#pragma unroll 4
        for (int m = 0; m < 64; m++) mx = fmaxf(mx, srow[m * 68]);

        float den = 0.f;
        float4 c0 = {0,0,0,0}, c1 = {0,0,0,0}, c2 = {0,0,0,0}, c3 = {0,0,0,0};
#pragma unroll 4
        for (int m = 0; m < 64; m++) {
            const float w = __expf(srow[m * 68] - mx);
            den += w;
            const float* mr = mean + m * 32;     // wave-uniform -> LDS broadcast
            const float4 m0 = *(const float4*)(mr);
            const float4 m1 = *(const float4*)(mr + 4);
            const float4 m2 = *(const float4*)(mr + 8);
            const float4 m3 = *(const float4*)(mr + 12);
            c0.x = fmaf(w, m0.x, c0.x); c0.y = fmaf(w, m0.y, c0.y);
            c0.z = fmaf(w, m0.z, c0.z); c0.w = fmaf(w, m0.w, c0.w);
            c1.x = fmaf(w, m1.x, c1.x); c1.y = fmaf(w, m1.y, c1.y);
            c1.z = fmaf(w, m1.z, c1.z); c1.w = fmaf(w, m1.w, c1.w);
            c2.x = fmaf(w, m2.x, c2.x); c2.y = fmaf(w, m2.y, c2.y);
            c2.z = fmaf(w, m2.z, c2.z); c2.w = fmaf(w, m2.w, c2.w);
            c3.x = fmaf(w, m3.x, c3.x); c3.y = fmaf(w, m3.y, c3.y);
            c3.z = fmaf(w, m3.z, c3.z); c3.w = fmaf(w, m3.w, c3.w);
        }
        const float sc = 1.f / den;
        float4* fp = (float4*)&fused[(size_t)(blk * 64 + r) * 64 + side * 32 + p0];
        float4 o0 = {c0.x*sc, c0.y*sc, c0.z*sc, c0.w*sc};
        float4 o1 = {c1.x*sc, c1.y*sc, c1.z*sc, c1.w*sc};
        float4 o2 = {c2.x*sc, c2.y*sc, c2.z*sc, c2.w*sc};
        float4 o3 = {c3.x*sc, c3.y*sc, c3.z*sc, c3.w*sc};
        fp[0] = o0; fp[1] = o1; fp[2] = o2; fp[3] = o3;
    }
}

// ====================================================================
// out: per block = one node n. nw = emb[n] @ pool (LDS), fused staged
// TRANSPOSED (fsT[f][b]) so inner loop is 2x ds_read_b128 per f.
// ====================================================================
__global__ __launch_bounds__(256) void dcmn_out(
    const float* __restrict__ emb,    // [1024][16]
    const float* __restrict__ pool,   // [16][64][64]
    const float* __restrict__ fused,  // [65536][64]
    float* __restrict__ out)          // [64][1024][64]
{
    __shared__ float nw[64 * 68];    // nodeW [f][h]
    __shared__ float fsT[64 * 68];   // fused transposed [f][b]
    __shared__ float es[16];
    const int t = threadIdx.x, n = blockIdx.x;

    if (t < 16) es[t] = emb[n * 16 + t];
#pragma unroll
    for (int i = 0; i < 4; i++) {
        const int idx = t + 256 * i;             // 1024 float4
        const int b = idx >> 4, c4 = idx & 15;
        const float4 v = *(const float4*)&fused[((size_t)b * kN + n) * 64 + c4 * 4];
        fsT[(c4 * 4 + 0) * 68 + b] = v.x;
        fsT[(c4 * 4 + 1) * 68 + b] = v.y;
        fsT[(c4 * 4 + 2) * 68 + b] = v.z;
        fsT[(c4 * 4 + 3) * 68 + b] = v.w;
    }
    __syncthreads();

    // node_w: 4096 outputs, K=16 (pool L2-resident, coalesced over h)
#pragma unroll
    for (int i = 0; i < 16; i++) {
        const int idx = t + 256 * i;
        const int f = idx >> 6, h = idx & 63;
        float a = 0.f;
#pragma unroll
        for (int d = 0; d < 16; d++)
            a = fmaf(es[d], pool[(d * 64 + f) * 64 + h], a);
        nw[f * 68 + h] = a;
    }
    __syncthreads();

    // out[b][h] = sum_f fsT[f][b] * nw[f][h]; thread tile 4b x 4h
    const int tb = t >> 4;      // b = tb*4 + i
    const int th = t & 15;      // h = th*4 + j  (h fastest -> coalesced stores)
    f32x4 o0 = {0,0,0,0}, o1 = {0,0,0,0}, o2 = {0,0,0,0}, o3 = {0,0,0,0};
#pragma unroll 8
    for (int f = 0; f < 64; f++) {
        const f32x4 a = *(const f32x4*)&fsT[f * 68 + tb * 4];
        const f32x4 w = *(const f32x4*)&nw[f * 68 + th * 4];
        o0 += w * a.x;
        o1 += w * a.y;
        o2 += w * a.z;
        o3 += w * a.w;
    }
    *(f32x4*)&out[((size_t)(tb * 4 + 0) * kN + n) * 64 + th * 4] = o0;
    *(f32x4*)&out[((size_t)(tb * 4 + 1) * kN + n) * 64 + th * 4] = o1;
    *(f32x4*)&out[((size_t)(tb * 4 + 2) * kN + n) * 64 + th * 4] = o2;
    *(f32x4*)&out[((size_t)(tb * 4 + 3) * kN + n) * 64 + th * 4] = o3;
}

// ====================================================================
extern "C" void kernel_launch(void* const* d_in, const int* in_sizes, int n_in,
                              void* d_out, int out_size, void* d_ws, size_t ws_size,
                              hipStream_t stream) {
    (void)in_sizes; (void)n_in; (void)out_size; (void)ws_size;
    const float* hist = (const float*)d_in[0];   // h_history
    const float* Gb   = (const float*)d_in[1];   // global_memory_bank
    const float* Lb   = (const float*)d_in[2];   // local_memory_bank
    const float* Wq   = (const float*)d_in[3];   // W_q
    const float* bq   = (const float*)d_in[4];   // b_q
    const float* emb  = (const float*)d_in[5];   // node_embedding
    const float* pool = (const float*)d_in[6];   // weight_pool
    float* outp = (float*)d_out;

    char* ws = (char*)d_ws;
    float* fused  = (float*)(ws + WS_FUSED);
    short* CtH    = (short*)(ws + WS_CTH);
    short* CtL    = (short*)(ws + WS_CTL);
    float* constv = (float*)(ws + WS_CONST);
    float* Lmean  = (float*)(ws + WS_LMEAN);
    float* Gmean  = (float*)(ws + WS_GMEAN);

    hipLaunchKernelGGL(dcmn_prep, dim3(128), dim3(256), 0, stream,
                       Gb, Lb, Wq, bq, CtH, CtL, constv, Lmean, Gmean);
    hipLaunchKernelGGL(dcmn_main, dim3(1024), dim3(256), 0, stream,
                       hist, CtH, CtL, constv, Lmean, Gmean, fused);
    hipLaunchKernelGGL(dcmn_out, dim3(1024), dim3(256), 0, stream,
                       emb, pool, fused, outp);
}